// Round 1
// baseline (9523.820 us; speedup 1.0000x reference)
//
#include <hip/hip_runtime.h>
#include <stdint.h>

#define BATCH 16
#define H 512
#define W 512
#define HW (H * W)
#define NTOT (BATCH * HW)

#define TPB 256
#define NBLK ((NTOT + TPB - 1) / TPB)

// ---------------------------------------------------------------------------
// Union-find helpers (Komura-style; atomicMin keeps parent[x] <= x monotone,
// so chains are acyclic and plain reads are safe — stale reads only retry).
// ---------------------------------------------------------------------------
__device__ __forceinline__ bool active_px(const uint8_t* m, int p, int inv) {
    return ((m[p] != 0) ^ (inv != 0));
}

__device__ __forceinline__ int find_root(int* L, int x) {
    int p = L[x];
    while (p != x) { x = p; p = L[x]; }
    return x;
}

__device__ void merge_uf(int* L, int a, int b) {
    while (true) {
        a = find_root(L, a);
        b = find_root(L, b);
        if (a == b) return;
        int lo = a < b ? a : b;
        int hi = a < b ? b : a;
        int old = atomicMin(&L[hi], lo);
        if (old == hi) return;   // linked a true root
        a = lo; b = old;         // root moved underneath us — retry
    }
}

// ---------------------------------------------------------------------------
// Kernels
// ---------------------------------------------------------------------------
__global__ void k_thresh(const float* __restrict__ in, uint8_t* __restrict__ fg) {
    int p = blockIdx.x * blockDim.x + threadIdx.x;
    if (p < NTOT) fg[p] = (in[p] > 0.0f) ? 1 : 0;
}

__global__ void k_init_labels(int* __restrict__ L) {
    int p = blockIdx.x * blockDim.x + threadIdx.x;
    if (p < NTOT) L[p] = p;
}

__global__ void k_merge(const uint8_t* __restrict__ m, int inv, int* L) {
    int p = blockIdx.x * blockDim.x + threadIdx.x;
    if (p >= NTOT) return;
    if (!active_px(m, p, inv)) return;
    int rem = p % HW;
    int x = rem % W;
    // left + up edges cover all 4-connectivity within the image
    if (x > 0 && active_px(m, p - 1, inv)) merge_uf(L, p, p - 1);
    if (rem >= W && active_px(m, p - W, inv)) merge_uf(L, p, p - W);
}

__global__ void k_flatten(const uint8_t* __restrict__ m, int inv, int* L) {
    int p = blockIdx.x * blockDim.x + threadIdx.x;
    if (p >= NTOT) return;
    if (!active_px(m, p, inv)) return;
    L[p] = find_root(L, p);
}

__global__ void k_count(const uint8_t* __restrict__ m, int inv,
                        const int* __restrict__ L,
                        int* __restrict__ sizes, int* __restrict__ ncomp) {
    int p = blockIdx.x * blockDim.x + threadIdx.x;
    if (p >= NTOT) return;
    if (!active_px(m, p, inv)) return;
    int r = L[p];
    atomicAdd(&sizes[r], 1);
    if (r == p) atomicAdd(&ncomp[p / HW], 1);  // one root per component
}

// remove_small_objects with the "only if label().max() > 1" guard
__global__ void k_keep_guard(const uint8_t* __restrict__ m, const int* __restrict__ L,
                             const int* __restrict__ sizes, const int* __restrict__ ncomp,
                             int minsz, uint8_t* __restrict__ out) {
    int p = blockIdx.x * blockDim.x + threadIdx.x;
    if (p >= NTOT) return;
    uint8_t f = m[p];
    if (f && ncomp[p / HW] > 1 && sizes[L[p]] < minsz) f = 0;
    out[p] = f;
}

// remove_small_holes: background components smaller than minsz become fg
__global__ void k_fill_holes(const uint8_t* __restrict__ m, const int* __restrict__ L,
                             const int* __restrict__ sizes, int minsz,
                             uint8_t* __restrict__ out) {
    int p = blockIdx.x * blockDim.x + threadIdx.x;
    if (p >= NTOT) return;
    uint8_t f = m[p];
    if (!f && sizes[L[p]] < minsz) f = 1;
    out[p] = f;
}

// disk-SE morphology; skimage border semantics: erosion pads 1, dilation pads 0
template <int R, bool ERODE>
__global__ void k_morph(const uint8_t* __restrict__ in, uint8_t* __restrict__ out) {
    int p = blockIdx.x * blockDim.x + threadIdx.x;
    if (p >= NTOT) return;
    int img = p / HW;
    int rem = p - img * HW;
    int y = rem / W;
    int x = rem - y * W;
    const uint8_t* base = in + (size_t)img * HW;
    bool res = ERODE;
#pragma unroll
    for (int dy = -R; dy <= R; ++dy) {
        int yy = y + dy;
        bool yin = (yy >= 0 && yy < H);
#pragma unroll
        for (int dx = -R; dx <= R; ++dx) {
            if (dy * dy + dx * dx > R * R) continue;  // disk mask (compile-time)
            int xx = x + dx;
            bool v;
            if (!yin || xx < 0 || xx >= W) v = ERODE;  // border value
            else v = base[yy * W + xx] != 0;
            if (ERODE) res = res && v; else res = res || v;
        }
    }
    out[p] = res ? 1 : 0;
}

__global__ void k_to_float(const uint8_t* __restrict__ fg, float* __restrict__ out) {
    int p = blockIdx.x * blockDim.x + threadIdx.x;
    if (p < NTOT) out[p] = fg[p] ? 1.0f : 0.0f;
}

// ---------------------------------------------------------------------------
// Host side
// ---------------------------------------------------------------------------
static void run_ccl(const uint8_t* mask, int inv, int* labels, int* sizes,
                    int* ncomp, hipStream_t stream) {
    hipMemsetAsync(sizes, 0, (size_t)NTOT * sizeof(int), stream);
    hipMemsetAsync(ncomp, 0, BATCH * sizeof(int), stream);
    k_init_labels<<<NBLK, TPB, 0, stream>>>(labels);
    k_merge<<<NBLK, TPB, 0, stream>>>(mask, inv, labels);
    k_flatten<<<NBLK, TPB, 0, stream>>>(mask, inv, labels);
    k_count<<<NBLK, TPB, 0, stream>>>(mask, inv, labels, sizes, ncomp);
}

extern "C" void kernel_launch(void* const* d_in, const int* in_sizes, int n_in,
                              void* d_out, int out_size, void* d_ws, size_t ws_size,
                              hipStream_t stream) {
    const float* in = (const float*)d_in[0];
    float* out = (float*)d_out;

    uint8_t* ws = (uint8_t*)d_ws;
    int* labels = (int*)ws;                                 // 16 MB
    int* sizes  = (int*)(ws + (size_t)NTOT * 4);            // 16 MB
    uint8_t* fgA = ws + (size_t)NTOT * 8;                   // 4 MB
    uint8_t* fgB = fgA + NTOT;                              // 4 MB
    int* ncomp = (int*)(fgB + NTOT);                        // 64 B

    // fg = mask > 0
    k_thresh<<<NBLK, TPB, 0, stream>>>(in, fgA);

    // remove_small_objects(fg, 2000, guard=True): fgA -> fgB
    run_ccl(fgA, 0, labels, sizes, ncomp, stream);
    k_keep_guard<<<NBLK, TPB, 0, stream>>>(fgA, labels, sizes, ncomp, 2000, fgB);

    // remove_small_holes (label background, fill comps < 301): fgB -> fgA
    run_ccl(fgB, 1, labels, sizes, ncomp, stream);
    k_fill_holes<<<NBLK, TPB, 0, stream>>>(fgB, labels, sizes, 301, fgA);

    // erode disk(2): fgA -> fgB
    k_morph<2, true><<<NBLK, TPB, 0, stream>>>(fgA, fgB);
    // opening disk(5): erode fgB -> fgA, dilate fgA -> fgB
    k_morph<5, true><<<NBLK, TPB, 0, stream>>>(fgB, fgA);
    k_morph<5, false><<<NBLK, TPB, 0, stream>>>(fgA, fgB);

    // remove_small_objects(fg, 2000, guard=True): fgB -> fgA
    run_ccl(fgB, 0, labels, sizes, ncomp, stream);
    k_keep_guard<<<NBLK, TPB, 0, stream>>>(fgB, labels, sizes, ncomp, 2000, fgA);

    // dilate disk(1): fgA -> fgB
    k_morph<1, false><<<NBLK, TPB, 0, stream>>>(fgA, fgB);

    // cast to float32
    k_to_float<<<NBLK, TPB, 0, stream>>>(fgB, out);
}

// Round 2
// 2294.478 us; speedup vs baseline: 4.1508x; 4.1508x over previous
//
#include <hip/hip_runtime.h>
#include <stdint.h>

#define BATCH 16
#define H 512
#define W 512
#define HW (H * W)
#define NTOT (BATCH * HW)

#define TPB 256
#define NBLK ((NTOT + TPB - 1) / TPB)

// ---------------------------------------------------------------------------
// Union-find helpers (atomicMin keeps parent[x] <= x monotone,
// so chains are acyclic and plain reads are safe — stale reads only retry).
// ---------------------------------------------------------------------------
__device__ __forceinline__ bool active_px(const uint8_t* m, int p, int inv) {
    return ((m[p] != 0) ^ (inv != 0));
}

__device__ __forceinline__ int find_root(int* L, int x) {
    int p = L[x];
    while (p != x) { x = p; p = L[x]; }
    return x;
}

__device__ void merge_uf(int* L, int a, int b) {
    while (true) {
        a = find_root(L, a);
        b = find_root(L, b);
        if (a == b) return;
        int lo = a < b ? a : b;
        int hi = a < b ? b : a;
        int old = atomicMin(&L[hi], lo);
        if (old == hi) return;   // linked a true root
        a = lo; b = old;         // root moved underneath us — retry
    }
}

// ---------------------------------------------------------------------------
// Kernels
// ---------------------------------------------------------------------------
__global__ void k_thresh(const float* __restrict__ in, uint8_t* __restrict__ fg) {
    int p = blockIdx.x * blockDim.x + threadIdx.x;
    if (p < NTOT) fg[p] = (in[p] > 0.0f) ? 1 : 0;
}

__global__ void k_init_labels(int* __restrict__ L) {
    int p = blockIdx.x * blockDim.x + threadIdx.x;
    if (p < NTOT) L[p] = p;
}

__global__ void k_merge(const uint8_t* __restrict__ m, int inv, int* L) {
    int p = blockIdx.x * blockDim.x + threadIdx.x;
    if (p >= NTOT) return;
    if (!active_px(m, p, inv)) return;
    int rem = p % HW;
    int x = rem % W;
    // left + up edges cover all 4-connectivity within the image
    if (x > 0 && active_px(m, p - 1, inv)) merge_uf(L, p, p - 1);
    if (rem >= W && active_px(m, p - W, inv)) merge_uf(L, p, p - W);
}

__global__ void k_flatten(const uint8_t* __restrict__ m, int inv, int* L) {
    int p = blockIdx.x * blockDim.x + threadIdx.x;
    if (p >= NTOT) return;
    if (!active_px(m, p, inv)) return;
    L[p] = find_root(L, p);
}

// Wave-aggregated component-size accumulation: after k_flatten labels are
// roots and spatially coherent, so a 64-lane wave spans ~1-2 distinct roots.
// Leader-election loop issues ONE atomicAdd per distinct root per wave
// (vs 64 per-lane atomics) — kills the single-address serialization on the
// giant background component.
__global__ void k_count(const uint8_t* __restrict__ m, int inv,
                        const int* __restrict__ L,
                        int* __restrict__ sizes, int* __restrict__ ncomp) {
    int p = blockIdx.x * blockDim.x + threadIdx.x;
    int r = -1;
    bool is_root = false;
    if (p < NTOT && active_px(m, p, inv)) {
        r = L[p];
        is_root = (r == p);
    }
    int lane = threadIdx.x & 63;
    unsigned long long alive = __ballot(r >= 0);
    while (alive) {
        int src = (int)(__ffsll((unsigned long long)alive) - 1);
        int lr = __shfl(r, src);                       // leader's root
        unsigned long long eq = __ballot(r == lr) & alive;
        if (lane == src) atomicAdd(&sizes[lr], (int)__popcll(eq));
        alive &= ~eq;
    }
    if (is_root) atomicAdd(&ncomp[p / HW], 1);  // one root per component (rare)
}

// remove_small_objects with the "only if label().max() > 1" guard
__global__ void k_keep_guard(const uint8_t* __restrict__ m, const int* __restrict__ L,
                             const int* __restrict__ sizes, const int* __restrict__ ncomp,
                             int minsz, uint8_t* __restrict__ out) {
    int p = blockIdx.x * blockDim.x + threadIdx.x;
    if (p >= NTOT) return;
    uint8_t f = m[p];
    if (f && ncomp[p / HW] > 1 && sizes[L[p]] < minsz) f = 0;
    out[p] = f;
}

// remove_small_holes: background components smaller than minsz become fg
__global__ void k_fill_holes(const uint8_t* __restrict__ m, const int* __restrict__ L,
                             const int* __restrict__ sizes, int minsz,
                             uint8_t* __restrict__ out) {
    int p = blockIdx.x * blockDim.x + threadIdx.x;
    if (p >= NTOT) return;
    uint8_t f = m[p];
    if (!f && sizes[L[p]] < minsz) f = 1;
    out[p] = f;
}

// disk-SE morphology; skimage border semantics: erosion pads 1, dilation pads 0
template <int R, bool ERODE>
__global__ void k_morph(const uint8_t* __restrict__ in, uint8_t* __restrict__ out) {
    int p = blockIdx.x * blockDim.x + threadIdx.x;
    if (p >= NTOT) return;
    int img = p / HW;
    int rem = p - img * HW;
    int y = rem / W;
    int x = rem - y * W;
    const uint8_t* base = in + (size_t)img * HW;
    bool res = ERODE;
#pragma unroll
    for (int dy = -R; dy <= R; ++dy) {
        int yy = y + dy;
        bool yin = (yy >= 0 && yy < H);
#pragma unroll
        for (int dx = -R; dx <= R; ++dx) {
            if (dy * dy + dx * dx > R * R) continue;  // disk mask (compile-time)
            int xx = x + dx;
            bool v;
            if (!yin || xx < 0 || xx >= W) v = ERODE;  // border value
            else v = base[yy * W + xx] != 0;
            if (ERODE) res = res && v; else res = res || v;
        }
    }
    out[p] = res ? 1 : 0;
}

__global__ void k_to_float(const uint8_t* __restrict__ fg, float* __restrict__ out) {
    int p = blockIdx.x * blockDim.x + threadIdx.x;
    if (p < NTOT) out[p] = fg[p] ? 1.0f : 0.0f;
}

// ---------------------------------------------------------------------------
// Host side
// ---------------------------------------------------------------------------
static void run_ccl(const uint8_t* mask, int inv, int* labels, int* sizes,
                    int* ncomp, hipStream_t stream) {
    hipMemsetAsync(sizes, 0, (size_t)NTOT * sizeof(int), stream);
    hipMemsetAsync(ncomp, 0, BATCH * sizeof(int), stream);
    k_init_labels<<<NBLK, TPB, 0, stream>>>(labels);
    k_merge<<<NBLK, TPB, 0, stream>>>(mask, inv, labels);
    k_flatten<<<NBLK, TPB, 0, stream>>>(mask, inv, labels);
    k_count<<<NBLK, TPB, 0, stream>>>(mask, inv, labels, sizes, ncomp);
}

extern "C" void kernel_launch(void* const* d_in, const int* in_sizes, int n_in,
                              void* d_out, int out_size, void* d_ws, size_t ws_size,
                              hipStream_t stream) {
    const float* in = (const float*)d_in[0];
    float* out = (float*)d_out;

    uint8_t* ws = (uint8_t*)d_ws;
    int* labels = (int*)ws;                                 // 16 MB
    int* sizes  = (int*)(ws + (size_t)NTOT * 4);            // 16 MB
    uint8_t* fgA = ws + (size_t)NTOT * 8;                   // 4 MB
    uint8_t* fgB = fgA + NTOT;                              // 4 MB
    int* ncomp = (int*)(fgB + NTOT);                        // 64 B

    // fg = mask > 0
    k_thresh<<<NBLK, TPB, 0, stream>>>(in, fgA);

    // remove_small_objects(fg, 2000, guard=True): fgA -> fgB
    run_ccl(fgA, 0, labels, sizes, ncomp, stream);
    k_keep_guard<<<NBLK, TPB, 0, stream>>>(fgA, labels, sizes, ncomp, 2000, fgB);

    // remove_small_holes (label background, fill comps < 301): fgB -> fgA
    run_ccl(fgB, 1, labels, sizes, ncomp, stream);
    k_fill_holes<<<NBLK, TPB, 0, stream>>>(fgB, labels, sizes, 301, fgA);

    // erode disk(2): fgA -> fgB
    k_morph<2, true><<<NBLK, TPB, 0, stream>>>(fgA, fgB);
    // opening disk(5): erode fgB -> fgA, dilate fgA -> fgB
    k_morph<5, true><<<NBLK, TPB, 0, stream>>>(fgB, fgA);
    k_morph<5, false><<<NBLK, TPB, 0, stream>>>(fgA, fgB);

    // remove_small_objects(fg, 2000, guard=True): fgB -> fgA
    run_ccl(fgB, 0, labels, sizes, ncomp, stream);
    k_keep_guard<<<NBLK, TPB, 0, stream>>>(fgB, labels, sizes, ncomp, 2000, fgA);

    // dilate disk(1): fgA -> fgB
    k_morph<1, false><<<NBLK, TPB, 0, stream>>>(fgA, fgB);

    // cast to float32
    k_to_float<<<NBLK, TPB, 0, stream>>>(fgB, out);
}

// Round 3
// 952.827 us; speedup vs baseline: 9.9953x; 2.4081x over previous
//
#include <hip/hip_runtime.h>
#include <stdint.h>
#include <string.h>

#define BATCH 16
#define H 512
#define W 512
#define HW (H * W)
#define NTOT (BATCH * HW)
#define NROWS (BATCH * H)

#define TPB 256
#define NBLK ((NTOT + TPB - 1) / TPB)

// ---------------------------------------------------------------------------
// Union-find helpers (atomicMin keeps parent[x] <= x monotone,
// so chains are acyclic and plain reads are safe — stale reads only retry).
// ---------------------------------------------------------------------------
__device__ __forceinline__ bool active_px(const uint8_t* m, int p, int inv) {
    return ((m[p] != 0) ^ (inv != 0));
}

__device__ __forceinline__ int find_root(int* L, int x) {
    int p = L[x];
    while (p != x) { x = p; p = L[x]; }
    return x;
}

__device__ void merge_uf(int* L, int a, int b) {
    while (true) {
        a = find_root(L, a);
        b = find_root(L, b);
        if (a == b) return;
        int lo = a < b ? a : b;
        int hi = a < b ? b : a;
        int old = atomicMin(&L[hi], lo);
        if (old == hi) return;   // linked a true root
        a = lo; b = old;         // root moved underneath us — retry
    }
}

// ---------------------------------------------------------------------------
// Kernels
// ---------------------------------------------------------------------------
__global__ void k_thresh(const float* __restrict__ in, uint8_t* __restrict__ fg) {
    int p = blockIdx.x * blockDim.x + threadIdx.x;
    if (p < NTOT) fg[p] = (in[p] > 0.0f) ? 1 : 0;
}

// Run-based label init: L[p] = index of the start of p's horizontal run of
// active pixels (L[p] = p for inactive). This encodes ALL horizontal
// connectivity with zero unions, and the array is already a valid union-find
// forest: non-start pixels point at their run start; run starts are roots.
// One wave per row; lane l handles bytes [8l, 8l+8).
__global__ void k_init_runs(const uint8_t* __restrict__ m, int inv,
                            int* __restrict__ L) {
    int wave = threadIdx.x >> 6;            // 0..3
    int lane = threadIdx.x & 63;
    int row = blockIdx.x * 4 + wave;        // exact: grid*4 == NROWS
    const uint8_t* rp = m + (size_t)row * W;
    int base = row * W + lane * 8;

    uint64_t v;
    memcpy(&v, rp + lane * 8, 8);
    uint32_t mask = 0;
#pragma unroll
    for (int i = 0; i < 8; ++i) {
        uint8_t b = (uint8_t)(v >> (8 * i));
        bool a = ((b != 0) ^ (inv != 0));
        mask |= (a ? 1u : 0u) << i;
    }
    bool full = (mask == 0xFFu);
    // start of the trailing run inside this chunk (valid only if bit7 set and
    // not full; if full the trailing run depends on the incoming carry)
    int trail = -1;
    if (mask & 0x80u) {
        uint32_t inv8 = (~mask) & 0xFFu;
        int lastZero = inv8 ? (31 - __builtin_clz(inv8)) : -1;
        trail = base + lastZero + 1;
    }

    __shared__ int s_full[4 * 64];
    __shared__ int s_trail[4 * 64];
    __shared__ int s_carry[4 * 64];
    s_full[threadIdx.x] = full ? 1 : 0;
    s_trail[threadIdx.x] = trail;
    __syncthreads();

    if (lane == 0) {   // sequential carry propagation across the 64 chunks
        int carry = -1;  // run start flowing in from the left (-1 = none)
        int rbase = row * W;
        for (int i = 0; i < 64; ++i) {
            int idx = wave * 64 + i;
            s_carry[idx] = carry;
            if (s_full[idx]) {
                if (carry < 0) carry = rbase + i * 8;
            } else {
                carry = s_trail[idx];
            }
        }
    }
    __syncthreads();

    int cur = s_carry[threadIdx.x];
#pragma unroll
    for (int i = 0; i < 8; ++i) {
        int p = base + i;
        if ((mask >> i) & 1u) {
            if (cur < 0) cur = p;
            L[p] = cur;
        } else {
            cur = -1;
            L[p] = p;
        }
    }
}

// Vertical unions, one per run-overlap segment: issue merge(p, p-W) only at
// the first column of each maximal overlap run (left/upleft not both active).
// Every other vertically adjacent pair is transitively covered (induction
// toward the segment start: same two runs involved).
__global__ void k_merge_runs(const uint8_t* __restrict__ m, int inv,
                             int* __restrict__ L) {
    int p = blockIdx.x * blockDim.x + threadIdx.x;
    if (p >= NTOT) return;
    if (!active_px(m, p, inv)) return;
    int rem = p % HW;
    if (rem < W) return;                       // first row of image
    if (!active_px(m, p - W, inv)) return;     // up neighbor inactive
    int x = rem % W;
    bool covered = (x > 0) && active_px(m, p - 1, inv) &&
                   active_px(m, p - W - 1, inv);
    if (!covered) merge_uf(L, p, p - W);
}

__global__ void k_flatten(const uint8_t* __restrict__ m, int inv, int* L) {
    int p = blockIdx.x * blockDim.x + threadIdx.x;
    if (p >= NTOT) return;
    if (!active_px(m, p, inv)) return;
    L[p] = find_root(L, p);
}

// Wave-aggregated component-size accumulation: one atomicAdd per distinct
// root per wave (leader election), not one per lane.
__global__ void k_count(const uint8_t* __restrict__ m, int inv,
                        const int* __restrict__ L,
                        int* __restrict__ sizes, int* __restrict__ ncomp) {
    int p = blockIdx.x * blockDim.x + threadIdx.x;
    int r = -1;
    bool is_root = false;
    if (p < NTOT && active_px(m, p, inv)) {
        r = L[p];
        is_root = (r == p);
    }
    int lane = threadIdx.x & 63;
    unsigned long long alive = __ballot(r >= 0);
    while (alive) {
        int src = (int)(__ffsll((unsigned long long)alive) - 1);
        int lr = __shfl(r, src);
        unsigned long long eq = __ballot(r == lr) & alive;
        if (lane == src) atomicAdd(&sizes[lr], (int)__popcll(eq));
        alive &= ~eq;
    }
    if (is_root) atomicAdd(&ncomp[p / HW], 1);
}

// remove_small_objects with the "only if label().max() > 1" guard
__global__ void k_keep_guard(const uint8_t* __restrict__ m, const int* __restrict__ L,
                             const int* __restrict__ sizes, const int* __restrict__ ncomp,
                             int minsz, uint8_t* __restrict__ out) {
    int p = blockIdx.x * blockDim.x + threadIdx.x;
    if (p >= NTOT) return;
    uint8_t f = m[p];
    if (f && ncomp[p / HW] > 1 && sizes[L[p]] < minsz) f = 0;
    out[p] = f;
}

// remove_small_holes: background components smaller than minsz become fg
__global__ void k_fill_holes(const uint8_t* __restrict__ m, const int* __restrict__ L,
                             const int* __restrict__ sizes, int minsz,
                             uint8_t* __restrict__ out) {
    int p = blockIdx.x * blockDim.x + threadIdx.x;
    if (p >= NTOT) return;
    uint8_t f = m[p];
    if (!f && sizes[L[p]] < minsz) f = 1;
    out[p] = f;
}

// disk-SE morphology; skimage border semantics: erosion pads 1, dilation pads 0.
// Center early-exit: blobs are wave-coherent, so ~half the waves skip all taps.
template <int R, bool ERODE>
__global__ void k_morph(const uint8_t* __restrict__ in, uint8_t* __restrict__ out) {
    int p = blockIdx.x * blockDim.x + threadIdx.x;
    if (p >= NTOT) return;
    bool c = in[p] != 0;
    if (ERODE ? !c : c) {       // erode: center 0 -> 0; dilate: center 1 -> 1
        out[p] = ERODE ? 0 : 1;
        return;
    }
    int img = p / HW;
    int rem = p - img * HW;
    int y = rem / W;
    int x = rem - y * W;
    const uint8_t* base = in + (size_t)img * HW;
    bool res = ERODE;
#pragma unroll
    for (int dy = -R; dy <= R; ++dy) {
        int yy = y + dy;
        bool yin = (yy >= 0 && yy < H);
#pragma unroll
        for (int dx = -R; dx <= R; ++dx) {
            if (dy * dy + dx * dx > R * R) continue;  // disk mask (compile-time)
            int xx = x + dx;
            bool v;
            if (!yin || xx < 0 || xx >= W) v = ERODE;  // border value
            else v = base[yy * W + xx] != 0;
            if (ERODE) res = res && v; else res = res || v;
        }
    }
    out[p] = res ? 1 : 0;
}

__global__ void k_to_float(const uint8_t* __restrict__ fg, float* __restrict__ out) {
    int p = blockIdx.x * blockDim.x + threadIdx.x;
    if (p < NTOT) out[p] = fg[p] ? 1.0f : 0.0f;
}

// ---------------------------------------------------------------------------
// Host side
// ---------------------------------------------------------------------------
static void run_ccl(const uint8_t* mask, int inv, int* labels, int* sizes,
                    int* ncomp, hipStream_t stream) {
    hipMemsetAsync(sizes, 0, (size_t)NTOT * sizeof(int), stream);
    hipMemsetAsync(ncomp, 0, BATCH * sizeof(int), stream);
    k_init_runs<<<NROWS / 4, 256, 0, stream>>>(mask, inv, labels);
    k_merge_runs<<<NBLK, TPB, 0, stream>>>(mask, inv, labels);
    k_flatten<<<NBLK, TPB, 0, stream>>>(mask, inv, labels);
    k_count<<<NBLK, TPB, 0, stream>>>(mask, inv, labels, sizes, ncomp);
}

extern "C" void kernel_launch(void* const* d_in, const int* in_sizes, int n_in,
                              void* d_out, int out_size, void* d_ws, size_t ws_size,
                              hipStream_t stream) {
    const float* in = (const float*)d_in[0];
    float* out = (float*)d_out;

    uint8_t* ws = (uint8_t*)d_ws;
    int* labels = (int*)ws;                                 // 16 MB
    int* sizes  = (int*)(ws + (size_t)NTOT * 4);            // 16 MB
    uint8_t* fgA = ws + (size_t)NTOT * 8;                   // 4 MB
    uint8_t* fgB = fgA + NTOT;                              // 4 MB
    int* ncomp = (int*)(fgB + NTOT);                        // 64 B

    // fg = mask > 0
    k_thresh<<<NBLK, TPB, 0, stream>>>(in, fgA);

    // remove_small_objects(fg, 2000, guard=True): fgA -> fgB
    run_ccl(fgA, 0, labels, sizes, ncomp, stream);
    k_keep_guard<<<NBLK, TPB, 0, stream>>>(fgA, labels, sizes, ncomp, 2000, fgB);

    // remove_small_holes (label background, fill comps < 301): fgB -> fgA
    run_ccl(fgB, 1, labels, sizes, ncomp, stream);
    k_fill_holes<<<NBLK, TPB, 0, stream>>>(fgB, labels, sizes, 301, fgA);

    // erode disk(2): fgA -> fgB
    k_morph<2, true><<<NBLK, TPB, 0, stream>>>(fgA, fgB);
    // opening disk(5): erode fgB -> fgA, dilate fgA -> fgB
    k_morph<5, true><<<NBLK, TPB, 0, stream>>>(fgB, fgA);
    k_morph<5, false><<<NBLK, TPB, 0, stream>>>(fgA, fgB);

    // remove_small_objects(fg, 2000, guard=True): fgB -> fgA
    run_ccl(fgB, 0, labels, sizes, ncomp, stream);
    k_keep_guard<<<NBLK, TPB, 0, stream>>>(fgB, labels, sizes, ncomp, 2000, fgA);

    // dilate disk(1): fgA -> fgB
    k_morph<1, false><<<NBLK, TPB, 0, stream>>>(fgA, fgB);

    // cast to float32
    k_to_float<<<NBLK, TPB, 0, stream>>>(fgB, out);
}

// Round 4
// 838.890 us; speedup vs baseline: 11.3529x; 1.1358x over previous
//
#include <hip/hip_runtime.h>
#include <stdint.h>

#define BATCH 16
#define H 512
#define W 512
#define HW (H * W)
#define NTOT (BATCH * HW)
#define NROWS (BATCH * H)
#define NWORDS (NTOT / 64)      // 65536 packed words, 8 per row

#define TPB 256
#define NBLK ((NTOT + TPB - 1) / TPB)
#define NBLKW ((NWORDS + TPB - 1) / TPB)

// ---------------------------------------------------------------------------
// Union-find helpers (atomicMin keeps parent[x] <= x monotone,
// so chains are acyclic and plain reads are safe — stale reads only retry).
// ---------------------------------------------------------------------------
__device__ __forceinline__ int find_root(int* L, int x) {
    int p = L[x];
    while (p != x) { x = p; p = L[x]; }
    return x;
}

__device__ void merge_uf(int* L, int a, int b) {
    while (true) {
        a = find_root(L, a);
        b = find_root(L, b);
        if (a == b) return;
        int lo = a < b ? a : b;
        int hi = a < b ? b : a;
        int old = atomicMin(&L[hi], lo);
        if (old == hi) return;
        a = lo; b = old;
    }
}

__device__ __forceinline__ bool bit_at(const uint64_t* m, int p, uint64_t inv64) {
    return ((m[p >> 6] ^ inv64) >> (p & 63)) & 1ull;
}

// ---------------------------------------------------------------------------
// Kernels — masks are bit-packed: bit i of word w = pixel w*64+i.
// ---------------------------------------------------------------------------
__global__ void k_thresh_pack(const float* __restrict__ in, uint64_t* __restrict__ bits) {
    int p = blockIdx.x * blockDim.x + threadIdx.x;
    bool a = (p < NTOT) && (in[p] > 0.0f);
    uint64_t b = __ballot(a);
    if ((threadIdx.x & 63) == 0 && p < NTOT) bits[p >> 6] = b;
}

// Run-based label init: L[p] = start index of p's horizontal run (L[p]=p for
// inactive). Encodes all horizontal connectivity with zero unions; array is a
// valid union-find forest. One wave per row; lane l reads byte l of the row
// bitmap (8 pixels).
__global__ void k_init_runs(const uint64_t* __restrict__ bits, int inv,
                            int* __restrict__ L) {
    int wave = threadIdx.x >> 6;
    int lane = threadIdx.x & 63;
    int row = blockIdx.x * 4 + wave;
    const uint8_t* rp = (const uint8_t*)(bits + (size_t)row * 8);
    int base = row * W + lane * 8;

    uint32_t mask = (uint32_t)rp[lane] ^ (inv ? 0xFFu : 0u);
    bool full = (mask == 0xFFu);
    int trail = -1;
    if (mask & 0x80u) {
        uint32_t inv8 = (~mask) & 0xFFu;
        int lastZero = inv8 ? (31 - __builtin_clz(inv8)) : -1;
        trail = base + lastZero + 1;
    }

    __shared__ int s_full[4 * 64];
    __shared__ int s_trail[4 * 64];
    __shared__ int s_carry[4 * 64];
    s_full[threadIdx.x] = full ? 1 : 0;
    s_trail[threadIdx.x] = trail;
    __syncthreads();

    if (lane == 0) {
        int carry = -1;
        int rbase = row * W;
        for (int i = 0; i < 64; ++i) {
            int idx = wave * 64 + i;
            s_carry[idx] = carry;
            if (s_full[idx]) {
                if (carry < 0) carry = rbase + i * 8;
            } else {
                carry = s_trail[idx];
            }
        }
    }
    __syncthreads();

    int cur = s_carry[threadIdx.x];
#pragma unroll
    for (int i = 0; i < 8; ++i) {
        int p = base + i;
        if ((mask >> i) & 1u) {
            if (cur < 0) cur = p;
            L[p] = cur;
        } else {
            cur = -1;
            L[p] = p;
        }
    }
}

// Vertical unions, one per run-overlap segment, word-per-thread:
// candidate bits = cur & up & ~(left & upleft); iterate set bits only.
__global__ void k_merge_runs(const uint64_t* __restrict__ m, int inv,
                             int* __restrict__ L) {
    int gw = blockIdx.x * blockDim.x + threadIdx.x;
    if (gw >= NWORDS) return;
    int wrow = gw & 7;
    int y = (gw >> 3) & (H - 1);
    if (y == 0) return;                        // first row of image
    uint64_t inv64 = inv ? ~0ull : 0ull;
    uint64_t cur = m[gw] ^ inv64;
    uint64_t up  = m[gw - 8] ^ inv64;
    uint64_t cand = cur & up;
    if (!cand) return;
    uint64_t curprev = wrow > 0 ? (m[gw - 1] ^ inv64) : 0ull;
    uint64_t upprev  = wrow > 0 ? (m[gw - 9] ^ inv64) : 0ull;
    uint64_t curl = (cur << 1) | (curprev >> 63);
    uint64_t upl  = (up << 1)  | (upprev >> 63);
    cand &= ~(curl & upl);
    int base = gw << 6;
    while (cand) {
        int i = (int)(__ffsll((unsigned long long)cand) - 1);
        merge_uf(L, base + i, base + i - W);
        cand &= cand - 1;
    }
}

// Fused flatten + wave-aggregated size/root counting.
__global__ void k_flatten_count(const uint64_t* __restrict__ m, int inv,
                                int* __restrict__ L,
                                int* __restrict__ sizes, int* __restrict__ ncomp) {
    int p = blockIdx.x * blockDim.x + threadIdx.x;
    uint64_t inv64 = inv ? ~0ull : 0ull;
    int r = -1;
    bool is_root = false;
    if (p < NTOT && bit_at(m, p, inv64)) {
        r = find_root(L, p);
        L[p] = r;
        is_root = (r == p);
    }
    int lane = threadIdx.x & 63;
    unsigned long long alive = __ballot(r >= 0);
    while (alive) {
        int src = (int)(__ffsll(alive) - 1);
        int lr = __shfl(r, src);
        unsigned long long eq = __ballot(r == lr) & alive;
        if (lane == src) atomicAdd(&sizes[lr], (int)__popcll(eq));
        alive &= ~eq;
    }
    if (is_root) atomicAdd(&ncomp[p >> 18], 1);   // HW = 2^18
}

// remove_small_objects with the "only if label().max() > 1" guard; packed out.
__global__ void k_keep_guard(const uint64_t* __restrict__ m, const int* __restrict__ L,
                             const int* __restrict__ sizes, const int* __restrict__ ncomp,
                             int minsz, uint64_t* __restrict__ out) {
    int p = blockIdx.x * blockDim.x + threadIdx.x;
    bool f = false;
    if (p < NTOT) {
        f = bit_at(m, p, 0ull);
        if (f && ncomp[p >> 18] > 1 && sizes[L[p]] < minsz) f = false;
    }
    uint64_t b = __ballot(f);
    if ((threadIdx.x & 63) == 0 && p < NTOT) out[p >> 6] = b;
}

// remove_small_holes: background components smaller than minsz become fg.
__global__ void k_fill_holes(const uint64_t* __restrict__ m, const int* __restrict__ L,
                             const int* __restrict__ sizes, int minsz,
                             uint64_t* __restrict__ out) {
    int p = blockIdx.x * blockDim.x + threadIdx.x;
    bool f = false;
    if (p < NTOT) {
        f = bit_at(m, p, 0ull);
        if (!f && sizes[L[p]] < minsz) f = true;
    }
    uint64_t b = __ballot(f);
    if ((threadIdx.x & 63) == 0 && p < NTOT) out[p >> 6] = b;
}

// Bit-packed disk morphology. Erode: AND over disk taps, border = 1s.
// Dilate: OR, border = 0s. OOB rows are identity -> skipped.
template <int R, bool ERODE>
__global__ void k_morph_bits(const uint64_t* __restrict__ in, uint64_t* __restrict__ out) {
    int gw = blockIdx.x * blockDim.x + threadIdx.x;
    if (gw >= NWORDS) return;
    int w = gw & 7;
    int y = (gw >> 3) & (H - 1);
    int b = gw >> 12;                   // word / (8*512)
    const uint64_t* img = in + (size_t)b * H * 8;
    const uint64_t BORDER = ERODE ? ~0ull : 0ull;
    uint64_t res = ERODE ? ~0ull : 0ull;
#pragma unroll
    for (int dy = -R; dy <= R; ++dy) {
        int yy = y + dy;
        if (yy < 0 || yy >= H) continue;        // border rows are identity
        // compile-time half-width of the disk at this dy
        int v = R * R - dy * dy;
        int kx = 0;
        while ((kx + 1) * (kx + 1) <= v) ++kx;
        uint64_t cur = img[yy * 8 + w];
        uint64_t prv = (w > 0) ? img[yy * 8 + w - 1] : BORDER;
        uint64_t nxt = (w < 7) ? img[yy * 8 + w + 1] : BORDER;
        uint64_t acc = cur;
#pragma unroll
        for (int dx = 1; dx <= kx; ++dx) {
            uint64_t right = (cur >> dx) | (nxt << (64 - dx));
            uint64_t left  = (cur << dx) | (prv >> (64 - dx));
            if (ERODE) acc &= right & left;
            else       acc |= right | left;
        }
        if (ERODE) res &= acc;
        else       res |= acc;
    }
    out[gw] = res;
}

__global__ void k_to_float(const uint64_t* __restrict__ bits, float* __restrict__ out) {
    int p = blockIdx.x * blockDim.x + threadIdx.x;
    if (p < NTOT) out[p] = ((bits[p >> 6] >> (p & 63)) & 1ull) ? 1.0f : 0.0f;
}

// ---------------------------------------------------------------------------
// Host side
// ---------------------------------------------------------------------------
static void run_ccl(const uint64_t* mask, int inv, int* labels, int* sizes,
                    int* ncomp, hipStream_t stream) {
    hipMemsetAsync(sizes, 0, (size_t)NTOT * sizeof(int), stream);
    hipMemsetAsync(ncomp, 0, BATCH * sizeof(int), stream);
    k_init_runs<<<NROWS / 4, 256, 0, stream>>>(mask, inv, labels);
    k_merge_runs<<<NBLKW, TPB, 0, stream>>>(mask, inv, labels);
    k_flatten_count<<<NBLK, TPB, 0, stream>>>(mask, inv, labels, sizes, ncomp);
}

extern "C" void kernel_launch(void* const* d_in, const int* in_sizes, int n_in,
                              void* d_out, int out_size, void* d_ws, size_t ws_size,
                              hipStream_t stream) {
    const float* in = (const float*)d_in[0];
    float* out = (float*)d_out;

    uint8_t* ws = (uint8_t*)d_ws;
    int* labels = (int*)ws;                                   // 16 MB
    int* sizes  = (int*)(ws + (size_t)NTOT * 4);              // 16 MB
    uint64_t* bitsA = (uint64_t*)(ws + (size_t)NTOT * 8);     // 512 KB
    uint64_t* bitsB = bitsA + NWORDS;                         // 512 KB
    int* ncomp = (int*)(bitsB + NWORDS);                      // 64 B

    // fg = mask > 0, packed
    k_thresh_pack<<<NBLK, TPB, 0, stream>>>(in, bitsA);

    // remove_small_objects(fg, 2000, guard=True): bitsA -> bitsB
    run_ccl(bitsA, 0, labels, sizes, ncomp, stream);
    k_keep_guard<<<NBLK, TPB, 0, stream>>>(bitsA, labels, sizes, ncomp, 2000, bitsB);

    // remove_small_holes (label background, fill comps < 301): bitsB -> bitsA
    run_ccl(bitsB, 1, labels, sizes, ncomp, stream);
    k_fill_holes<<<NBLK, TPB, 0, stream>>>(bitsB, labels, sizes, 301, bitsA);

    // erode disk(2): A -> B; opening disk(5): erode B -> A, dilate A -> B
    k_morph_bits<2, true><<<NBLKW, TPB, 0, stream>>>(bitsA, bitsB);
    k_morph_bits<5, true><<<NBLKW, TPB, 0, stream>>>(bitsB, bitsA);
    k_morph_bits<5, false><<<NBLKW, TPB, 0, stream>>>(bitsA, bitsB);

    // remove_small_objects(fg, 2000, guard=True): bitsB -> bitsA
    run_ccl(bitsB, 0, labels, sizes, ncomp, stream);
    k_keep_guard<<<NBLK, TPB, 0, stream>>>(bitsB, labels, sizes, ncomp, 2000, bitsA);

    // dilate disk(1): A -> B
    k_morph_bits<1, false><<<NBLKW, TPB, 0, stream>>>(bitsA, bitsB);

    // cast to float32
    k_to_float<<<NBLK, TPB, 0, stream>>>(bitsB, out);
}

// Round 5
// 400.970 us; speedup vs baseline: 23.7520x; 2.0922x over previous
//
#include <hip/hip_runtime.h>
#include <stdint.h>

#define BATCH 16
#define H 512
#define W 512
#define HW (H * W)
#define NTOT (BATCH * HW)
#define NROWS (BATCH * H)
#define NWORDS (NTOT / 64)      // 65536 packed words, 8 per row, 4096 per image

#define TPB 256
#define NBLK ((NTOT + TPB - 1) / TPB)
#define NBLKW ((NWORDS + TPB - 1) / TPB)

// ---------------------------------------------------------------------------
// Union-find over RUN-START indices only (sparse in a NTOT-sized array).
// atomicMin keeps parent <= child (monotone) so races only cost retries.
// find_root_c adds path compression via atomicMin (safe: root <= any stale).
// ---------------------------------------------------------------------------
__device__ __forceinline__ int find_root_c(int* L, int x) {
    int r = x, p = L[r];
    while (p != r) { r = p; p = L[r]; }
    if (L[x] != r) atomicMin(&L[x], r);
    return r;
}

__device__ void merge_uf(int* L, int a, int b) {
    while (true) {
        a = find_root_c(L, a);
        b = find_root_c(L, b);
        if (a == b) return;
        int lo = a < b ? a : b;
        int hi = a < b ? b : a;
        int old = atomicMin(&L[hi], lo);
        if (old == hi) return;
        a = lo; b = old;
    }
}

// start index of the run containing bit i of word m (base = word<<6);
// cv = carry into this word (run start continuing from the left, -1 if none)
__device__ __forceinline__ int start_of(uint64_t m, int i, int cv, int base) {
    uint64_t below = i ? ((~m) & ((1ull << i) - 1)) : 0ull;
    if (below == 0) return (cv >= 0) ? cv : base;  // bits 0..i-1 all ones
    int hz = 63 - __builtin_clzll(below);          // highest zero below i
    return base + hz + 1;
}

// ---------------------------------------------------------------------------
// Kernels — masks bit-packed: bit i of word w = pixel w*64+i.
// ---------------------------------------------------------------------------
__global__ void k_thresh_pack(const float* __restrict__ in, uint64_t* __restrict__ bits) {
    int p = blockIdx.x * blockDim.x + threadIdx.x;
    bool a = (p < NTOT) && (in[p] > 0.0f);
    uint64_t b = __ballot(a);
    if ((threadIdx.x & 63) == 0 && p < NTOT) bits[p >> 6] = b;
}

// One thread per row: compute per-word carry (run start continuing into the
// word), init L[start]=start and sizes[start]=0 sparsely at run starts.
// Also clears ncomp (one thread per image).
__global__ void k_init_runs(const uint64_t* __restrict__ bits, int inv,
                            int* __restrict__ carry, int* __restrict__ L,
                            int* __restrict__ sizes, int* __restrict__ ncomp) {
    int row = blockIdx.x * blockDim.x + threadIdx.x;
    if (row >= NROWS) return;
    if ((row & (H - 1)) == 0) ncomp[row >> 9] = 0;
    uint64_t inv64 = inv ? ~0ull : 0ull;
    const uint64_t* bw = bits + (size_t)row * 8;
    int cv = -1;
#pragma unroll
    for (int i = 0; i < 8; ++i) {
        int w = row * 8 + i;
        uint64_t m = bw[i] ^ inv64;
        carry[w] = cv;
        uint64_t starts = m & ~((m << 1) | (cv >= 0 ? 1ull : 0ull));
        int base = w << 6;
        while (starts) {
            int s = __builtin_ctzll(starts);
            int st = base + s;
            L[st] = st;
            sizes[st] = 0;
            starts &= starts - 1;
        }
        if (m >> 63) {
            uint64_t t = ~m;
            if (t == 0) { if (cv < 0) cv = base; }
            else { int hz = 63 - __builtin_clzll(t); cv = base + hz + 1; }
        } else {
            cv = -1;
        }
    }
}

// Vertical unions, one per run-overlap segment, word-per-thread, run-granular.
__global__ void k_merge_runs(const uint64_t* __restrict__ bits, int inv,
                             const int* __restrict__ carry, int* __restrict__ L) {
    int gw = blockIdx.x * blockDim.x + threadIdx.x;
    if (gw >= NWORDS) return;
    int wrow = gw & 7;
    int y = (gw >> 3) & (H - 1);
    if (y == 0) return;
    uint64_t inv64 = inv ? ~0ull : 0ull;
    uint64_t cur = bits[gw] ^ inv64;
    uint64_t up  = bits[gw - 8] ^ inv64;
    uint64_t cand = cur & up;
    if (!cand) return;
    uint64_t curprev = wrow ? (bits[gw - 1] ^ inv64) : 0ull;
    uint64_t upprev  = wrow ? (bits[gw - 9] ^ inv64) : 0ull;
    uint64_t curl = (cur << 1) | (curprev >> 63);
    uint64_t upl  = (up << 1)  | (upprev >> 63);
    cand &= ~(curl & upl);
    if (!cand) return;
    int cvc = carry[gw], cvu = carry[gw - 8];
    int base = gw << 6;
    while (cand) {
        int i = __builtin_ctzll(cand);
        int sP = start_of(cur, i, cvc, base);
        int sQ = start_of(up, i, cvu, base - W);
        merge_uf(L, sP, sQ);
        cand &= cand - 1;
    }
}

// Word-granular flatten + size accumulation. Per-block LDS hash (root->count)
// aggregates the size atomics; flush one global atomicAdd per occupied slot.
__global__ void k_flatten_count(const uint64_t* __restrict__ bits, int inv,
                                const int* __restrict__ carry, int* __restrict__ L,
                                int* __restrict__ sizes, int* __restrict__ ncomp) {
    __shared__ int hk[128];
    __shared__ int hv[128];
    for (int i = threadIdx.x; i < 128; i += TPB) { hk[i] = -1; hv[i] = 0; }
    __syncthreads();

    int gw = blockIdx.x * blockDim.x + threadIdx.x;
    if (gw < NWORDS) {
        uint64_t inv64 = inv ? ~0ull : 0ull;
        uint64_t m = bits[gw] ^ inv64;
        if (m) {
            int cv = carry[gw];
            int base = gw << 6;
            while (m) {
                int s = __builtin_ctzll(m);
                uint64_t rest = m >> s;
                uint64_t nr = ~rest;
                int len = nr ? __builtin_ctzll(nr) : (64 - s);
                uint64_t piece = ((len >= 64) ? ~0ull : ((1ull << len) - 1)) << s;
                bool initial = !(s == 0 && cv >= 0);
                int start = initial ? (base + s) : cv;
                int r = find_root_c(L, start);
                if (initial && r == start) atomicAdd(&ncomp[gw >> 12], 1);
                int cnt = __popcll(piece);
                // LDS hash insert with linear probing; fallback to global
                uint32_t h = ((uint32_t)r * 2654435761u) >> 25;
                bool done = false;
                for (int t = 0; t < 16; ++t) {
                    int slot = (h + t) & 127;
                    int k = hk[slot];
                    if (k == -1) k = atomicCAS(&hk[slot], -1, r);
                    if (k == -1 || k == r) { atomicAdd(&hv[slot], cnt); done = true; break; }
                }
                if (!done) atomicAdd(&sizes[r], cnt);
                m &= ~piece;
            }
        }
    }
    __syncthreads();
    for (int i = threadIdx.x; i < 128; i += TPB)
        if (hk[i] != -1) atomicAdd(&sizes[hk[i]], hv[i]);
}

// remove_small_objects with guard, word-granular (inv=0 CCL data).
__global__ void k_keep_guard(const uint64_t* __restrict__ bits,
                             const int* __restrict__ carry, const int* __restrict__ L,
                             const int* __restrict__ sizes, const int* __restrict__ ncomp,
                             int minsz, uint64_t* __restrict__ out) {
    int gw = blockIdx.x * blockDim.x + threadIdx.x;
    if (gw >= NWORDS) return;
    uint64_t m = bits[gw];
    uint64_t res = m;
    if (m && ncomp[gw >> 12] > 1) {
        int cv = carry[gw];
        int base = gw << 6;
        while (m) {
            int s = __builtin_ctzll(m);
            uint64_t rest = m >> s;
            uint64_t nr = ~rest;
            int len = nr ? __builtin_ctzll(nr) : (64 - s);
            uint64_t piece = ((len >= 64) ? ~0ull : ((1ull << len) - 1)) << s;
            int start = (s == 0 && cv >= 0) ? cv : (base + s);
            int r = L[start];                  // flattened by k_flatten_count
            if (sizes[r] < minsz) res &= ~piece;
            m &= ~piece;
        }
    }
    out[gw] = res;
}

// remove_small_holes: bg components (inv=1 CCL data) smaller than minsz -> fg.
__global__ void k_fill_holes(const uint64_t* __restrict__ bits,
                             const int* __restrict__ carry, const int* __restrict__ L,
                             const int* __restrict__ sizes, int minsz,
                             uint64_t* __restrict__ out) {
    int gw = blockIdx.x * blockDim.x + threadIdx.x;
    if (gw >= NWORDS) return;
    uint64_t fg = bits[gw];
    uint64_t bg = ~fg;
    uint64_t res = fg;
    int cv = carry[gw];
    int base = gw << 6;
    while (bg) {
        int s = __builtin_ctzll(bg);
        uint64_t rest = bg >> s;
        uint64_t nr = ~rest;
        int len = nr ? __builtin_ctzll(nr) : (64 - s);
        uint64_t piece = ((len >= 64) ? ~0ull : ((1ull << len) - 1)) << s;
        int start = (s == 0 && cv >= 0) ? cv : (base + s);
        int r = L[start];
        if (sizes[r] < minsz) res |= piece;
        bg &= ~piece;
    }
    out[gw] = res;
}

// Bit-packed disk morphology. Erode: AND, border = 1s. Dilate: OR, border = 0s.
template <int R, bool ERODE>
__global__ void k_morph_bits(const uint64_t* __restrict__ in, uint64_t* __restrict__ out) {
    int gw = blockIdx.x * blockDim.x + threadIdx.x;
    if (gw >= NWORDS) return;
    int w = gw & 7;
    int y = (gw >> 3) & (H - 1);
    int b = gw >> 12;
    const uint64_t* img = in + (size_t)b * H * 8;
    const uint64_t BORDER = ERODE ? ~0ull : 0ull;
    uint64_t res = ERODE ? ~0ull : 0ull;
#pragma unroll
    for (int dy = -R; dy <= R; ++dy) {
        int yy = y + dy;
        if (yy < 0 || yy >= H) continue;
        int v = R * R - dy * dy;
        int kx = 0;
        while ((kx + 1) * (kx + 1) <= v) ++kx;
        uint64_t cur = img[yy * 8 + w];
        uint64_t prv = (w > 0) ? img[yy * 8 + w - 1] : BORDER;
        uint64_t nxt = (w < 7) ? img[yy * 8 + w + 1] : BORDER;
        uint64_t acc = cur;
#pragma unroll
        for (int dx = 1; dx <= kx; ++dx) {
            uint64_t right = (cur >> dx) | (nxt << (64 - dx));
            uint64_t left  = (cur << dx) | (prv >> (64 - dx));
            if (ERODE) acc &= right & left;
            else       acc |= right | left;
        }
        if (ERODE) res &= acc;
        else       res |= acc;
    }
    out[gw] = res;
}

__global__ void k_to_float(const uint64_t* __restrict__ bits, float* __restrict__ out) {
    int p = blockIdx.x * blockDim.x + threadIdx.x;
    if (p < NTOT) out[p] = ((bits[p >> 6] >> (p & 63)) & 1ull) ? 1.0f : 0.0f;
}

// ---------------------------------------------------------------------------
// Host side
// ---------------------------------------------------------------------------
static void run_ccl(const uint64_t* mask, int inv, int* carry, int* labels,
                    int* sizes, int* ncomp, hipStream_t stream) {
    k_init_runs<<<(NROWS + TPB - 1) / TPB, TPB, 0, stream>>>(mask, inv, carry, labels, sizes, ncomp);
    k_merge_runs<<<NBLKW, TPB, 0, stream>>>(mask, inv, carry, labels);
    k_flatten_count<<<NBLKW, TPB, 0, stream>>>(mask, inv, carry, labels, sizes, ncomp);
}

extern "C" void kernel_launch(void* const* d_in, const int* in_sizes, int n_in,
                              void* d_out, int out_size, void* d_ws, size_t ws_size,
                              hipStream_t stream) {
    const float* in = (const float*)d_in[0];
    float* out = (float*)d_out;

    uint8_t* ws = (uint8_t*)d_ws;
    int* labels = (int*)ws;                                   // 16 MB (sparse use)
    int* sizes  = (int*)(ws + (size_t)NTOT * 4);              // 16 MB (sparse use)
    uint64_t* bitsA = (uint64_t*)(ws + (size_t)NTOT * 8);     // 512 KB
    uint64_t* bitsB = bitsA + NWORDS;                         // 512 KB
    int* carry = (int*)(bitsB + NWORDS);                      // 256 KB
    int* ncomp = carry + NWORDS;                              // 64 B

    // fg = mask > 0, packed
    k_thresh_pack<<<NBLK, TPB, 0, stream>>>(in, bitsA);

    // remove_small_objects(fg, 2000, guard=True): bitsA -> bitsB
    run_ccl(bitsA, 0, carry, labels, sizes, ncomp, stream);
    k_keep_guard<<<NBLKW, TPB, 0, stream>>>(bitsA, carry, labels, sizes, ncomp, 2000, bitsB);

    // remove_small_holes (bg comps < 301 filled): bitsB -> bitsA
    run_ccl(bitsB, 1, carry, labels, sizes, ncomp, stream);
    k_fill_holes<<<NBLKW, TPB, 0, stream>>>(bitsB, carry, labels, sizes, 301, bitsA);

    // erode disk(2): A -> B; opening disk(5): erode B -> A, dilate A -> B
    k_morph_bits<2, true><<<NBLKW, TPB, 0, stream>>>(bitsA, bitsB);
    k_morph_bits<5, true><<<NBLKW, TPB, 0, stream>>>(bitsB, bitsA);
    k_morph_bits<5, false><<<NBLKW, TPB, 0, stream>>>(bitsA, bitsB);

    // remove_small_objects(fg, 2000, guard=True): bitsB -> bitsA
    run_ccl(bitsB, 0, carry, labels, sizes, ncomp, stream);
    k_keep_guard<<<NBLKW, TPB, 0, stream>>>(bitsB, carry, labels, sizes, ncomp, 2000, bitsA);

    // dilate disk(1): A -> B
    k_morph_bits<1, false><<<NBLKW, TPB, 0, stream>>>(bitsA, bitsB);

    // cast to float32
    k_to_float<<<NBLK, TPB, 0, stream>>>(bitsB, out);
}

// Round 6
// 323.467 us; speedup vs baseline: 29.4430x; 1.2396x over previous
//
#include <hip/hip_runtime.h>
#include <stdint.h>

#define BATCH 16
#define H 512
#define W 512
#define HW (H * W)
#define NTOT (BATCH * HW)
#define NROWS (BATCH * H)
#define NWORDS (NTOT / 64)      // 65536 packed words, 8 per row, 4096 per image

#define TPB 256
#define NBLK ((NTOT + TPB - 1) / TPB)
#define NBLKW ((NWORDS + TPB - 1) / TPB)

// ---------------------------------------------------------------------------
// Union-find over RUN-START indices only (sparse in a NTOT-sized array).
// atomicMin keeps parent <= child (monotone) so races only cost retries.
// find_root_c adds path compression via atomicMin (safe: root <= any stale).
// ---------------------------------------------------------------------------
__device__ __forceinline__ int find_root_c(int* L, int x) {
    int r = x, p = L[r];
    while (p != r) { r = p; p = L[r]; }
    if (L[x] != r) atomicMin(&L[x], r);
    return r;
}

__device__ void merge_uf(int* L, int a, int b) {
    while (true) {
        a = find_root_c(L, a);
        b = find_root_c(L, b);
        if (a == b) return;
        int lo = a < b ? a : b;
        int hi = a < b ? b : a;
        int old = atomicMin(&L[hi], lo);
        if (old == hi) return;
        a = lo; b = old;
    }
}

// start index of the run containing bit i of word m (base = word<<6);
// cv = carry into this word (run start continuing from the left, -1 if none)
__device__ __forceinline__ int start_of(uint64_t m, int i, int cv, int base) {
    uint64_t below = i ? ((~m) & ((1ull << i) - 1)) : 0ull;
    if (below == 0) return (cv >= 0) ? cv : base;  // bits 0..i-1 all ones
    int hz = 63 - __builtin_clzll(below);          // highest zero below i
    return base + hz + 1;
}

// ---------------------------------------------------------------------------
// Kernels — masks bit-packed: bit i of word w = pixel w*64+i.
// ---------------------------------------------------------------------------
__global__ void k_thresh_pack(const float* __restrict__ in, uint64_t* __restrict__ bits) {
    int p = blockIdx.x * blockDim.x + threadIdx.x;
    bool a = (p < NTOT) && (in[p] > 0.0f);
    uint64_t b = __ballot(a);
    if ((threadIdx.x & 63) == 0 && p < NTOT) bits[p >> 6] = b;
}

// One thread per row: compute per-word carry (run start continuing into the
// word), init L[start]=start and sizes[start]=0 sparsely at run starts.
__global__ void k_init_runs(const uint64_t* __restrict__ bits, int inv,
                            int* __restrict__ carry, int* __restrict__ L,
                            int* __restrict__ sizes, int* __restrict__ ncomp) {
    int row = blockIdx.x * blockDim.x + threadIdx.x;
    if (row >= NROWS) return;
    if ((row & (H - 1)) == 0) ncomp[row >> 9] = 0;
    uint64_t inv64 = inv ? ~0ull : 0ull;
    const uint64_t* bw = bits + (size_t)row * 8;
    int cv = -1;
#pragma unroll
    for (int i = 0; i < 8; ++i) {
        int w = row * 8 + i;
        uint64_t m = bw[i] ^ inv64;
        carry[w] = cv;
        uint64_t starts = m & ~((m << 1) | (cv >= 0 ? 1ull : 0ull));
        int base = w << 6;
        while (starts) {
            int s = __builtin_ctzll(starts);
            int st = base + s;
            L[st] = st;
            sizes[st] = 0;
            starts &= starts - 1;
        }
        if (m >> 63) {
            uint64_t t = ~m;
            if (t == 0) { if (cv < 0) cv = base; }
            else { int hz = 63 - __builtin_clzll(t); cv = base + hz + 1; }
        } else {
            cv = -1;
        }
    }
}

// Vertical unions, one per run-overlap segment, word-per-thread, run-granular.
// Strip-hierarchical: phase 0 handles rows with y%32!=0 (chains confined to
// 32-row strips); phase 1 handles strip-boundary rows y%32==0 (links strip
// trees — short, progressively compressed chains). Covers every adjacency once.
__global__ void k_merge_runs(const uint64_t* __restrict__ bits, int inv,
                             const int* __restrict__ carry, int* __restrict__ L,
                             int phase) {
    int gw = blockIdx.x * blockDim.x + threadIdx.x;
    if (gw >= NWORDS) return;
    int wrow = gw & 7;
    int y = (gw >> 3) & (H - 1);
    if (y == 0) return;
    bool boundary = (y & 31) == 0;
    if (phase == 0 ? boundary : !boundary) return;
    uint64_t inv64 = inv ? ~0ull : 0ull;
    uint64_t cur = bits[gw] ^ inv64;
    uint64_t up  = bits[gw - 8] ^ inv64;
    uint64_t cand = cur & up;
    if (!cand) return;
    uint64_t curprev = wrow ? (bits[gw - 1] ^ inv64) : 0ull;
    uint64_t upprev  = wrow ? (bits[gw - 9] ^ inv64) : 0ull;
    uint64_t curl = (cur << 1) | (curprev >> 63);
    uint64_t upl  = (up << 1)  | (upprev >> 63);
    cand &= ~(curl & upl);
    if (!cand) return;
    int cvc = carry[gw], cvu = carry[gw - 8];
    int base = gw << 6;
    while (cand) {
        int i = __builtin_ctzll(cand);
        int sP = start_of(cur, i, cvc, base);
        int sQ = start_of(up, i, cvu, base - W);
        merge_uf(L, sP, sQ);
        cand &= cand - 1;
    }
}

// Word-granular flatten + size accumulation. Per-block LDS hash (root->count)
// aggregates the size atomics; flush one global atomicAdd per occupied slot.
__global__ void k_flatten_count(const uint64_t* __restrict__ bits, int inv,
                                const int* __restrict__ carry, int* __restrict__ L,
                                int* __restrict__ sizes, int* __restrict__ ncomp) {
    __shared__ int hk[128];
    __shared__ int hv[128];
    for (int i = threadIdx.x; i < 128; i += TPB) { hk[i] = -1; hv[i] = 0; }
    __syncthreads();

    int gw = blockIdx.x * blockDim.x + threadIdx.x;
    if (gw < NWORDS) {
        uint64_t inv64 = inv ? ~0ull : 0ull;
        uint64_t m = bits[gw] ^ inv64;
        if (m) {
            int cv = carry[gw];
            int base = gw << 6;
            while (m) {
                int s = __builtin_ctzll(m);
                uint64_t rest = m >> s;
                uint64_t nr = ~rest;
                int len = nr ? __builtin_ctzll(nr) : (64 - s);
                uint64_t piece = ((len >= 64) ? ~0ull : ((1ull << len) - 1)) << s;
                bool initial = !(s == 0 && cv >= 0);
                int start = initial ? (base + s) : cv;
                int r = find_root_c(L, start);
                if (initial && r == start) atomicAdd(&ncomp[gw >> 12], 1);
                int cnt = __popcll(piece);
                uint32_t h = ((uint32_t)r * 2654435761u) >> 25;
                bool done = false;
                for (int t = 0; t < 16; ++t) {
                    int slot = (h + t) & 127;
                    int k = hk[slot];
                    if (k == -1) k = atomicCAS(&hk[slot], -1, r);
                    if (k == -1 || k == r) { atomicAdd(&hv[slot], cnt); done = true; break; }
                }
                if (!done) atomicAdd(&sizes[r], cnt);
                m &= ~piece;
            }
        }
    }
    __syncthreads();
    for (int i = threadIdx.x; i < 128; i += TPB)
        if (hk[i] != -1) atomicAdd(&sizes[hk[i]], hv[i]);
}

// remove_small_objects with guard, word-granular (inv=0 CCL data).
__global__ void k_keep_guard(const uint64_t* __restrict__ bits,
                             const int* __restrict__ carry, const int* __restrict__ L,
                             const int* __restrict__ sizes, const int* __restrict__ ncomp,
                             int minsz, uint64_t* __restrict__ out) {
    int gw = blockIdx.x * blockDim.x + threadIdx.x;
    if (gw >= NWORDS) return;
    uint64_t m = bits[gw];
    uint64_t res = m;
    if (m && ncomp[gw >> 12] > 1) {
        int cv = carry[gw];
        int base = gw << 6;
        while (m) {
            int s = __builtin_ctzll(m);
            uint64_t rest = m >> s;
            uint64_t nr = ~rest;
            int len = nr ? __builtin_ctzll(nr) : (64 - s);
            uint64_t piece = ((len >= 64) ? ~0ull : ((1ull << len) - 1)) << s;
            int start = (s == 0 && cv >= 0) ? cv : (base + s);
            int r = L[start];                  // flattened by k_flatten_count
            if (sizes[r] < minsz) res &= ~piece;
            m &= ~piece;
        }
    }
    out[gw] = res;
}

// remove_small_holes: bg components (inv=1 CCL data) smaller than minsz -> fg.
__global__ void k_fill_holes(const uint64_t* __restrict__ bits,
                             const int* __restrict__ carry, const int* __restrict__ L,
                             const int* __restrict__ sizes, int minsz,
                             uint64_t* __restrict__ out) {
    int gw = blockIdx.x * blockDim.x + threadIdx.x;
    if (gw >= NWORDS) return;
    uint64_t fg = bits[gw];
    uint64_t bg = ~fg;
    uint64_t res = fg;
    int cv = carry[gw];
    int base = gw << 6;
    while (bg) {
        int s = __builtin_ctzll(bg);
        uint64_t rest = bg >> s;
        uint64_t nr = ~rest;
        int len = nr ? __builtin_ctzll(nr) : (64 - s);
        uint64_t piece = ((len >= 64) ? ~0ull : ((1ull << len) - 1)) << s;
        int start = (s == 0 && cv >= 0) ? cv : (base + s);
        int r = L[start];
        if (sizes[r] < minsz) res |= piece;
        bg &= ~piece;
    }
    out[gw] = res;
}

// Bit-packed disk morphology. Erode: AND, border = 1s. Dilate: OR, border = 0s.
template <int R, bool ERODE>
__global__ void k_morph_bits(const uint64_t* __restrict__ in, uint64_t* __restrict__ out) {
    int gw = blockIdx.x * blockDim.x + threadIdx.x;
    if (gw >= NWORDS) return;
    int w = gw & 7;
    int y = (gw >> 3) & (H - 1);
    int b = gw >> 12;
    const uint64_t* img = in + (size_t)b * H * 8;
    const uint64_t BORDER = ERODE ? ~0ull : 0ull;
    uint64_t res = ERODE ? ~0ull : 0ull;
#pragma unroll
    for (int dy = -R; dy <= R; ++dy) {
        int yy = y + dy;
        if (yy < 0 || yy >= H) continue;
        int v = R * R - dy * dy;
        int kx = 0;
        while ((kx + 1) * (kx + 1) <= v) ++kx;
        uint64_t cur = img[yy * 8 + w];
        uint64_t prv = (w > 0) ? img[yy * 8 + w - 1] : BORDER;
        uint64_t nxt = (w < 7) ? img[yy * 8 + w + 1] : BORDER;
        uint64_t acc = cur;
#pragma unroll
        for (int dx = 1; dx <= kx; ++dx) {
            uint64_t right = (cur >> dx) | (nxt << (64 - dx));
            uint64_t left  = (cur << dx) | (prv >> (64 - dx));
            if (ERODE) acc &= right & left;
            else       acc |= right | left;
        }
        if (ERODE) res &= acc;
        else       res |= acc;
    }
    out[gw] = res;
}

// Fused dilate(disk1) + float cast: disk(1) is the plus-shaped SE, so the
// dilated word is OR of {cur, up, down, cur<<1|prv>>63, cur>>1|nxt<<63}.
__global__ void k_to_float_dilate(const uint64_t* __restrict__ bits,
                                  float* __restrict__ out) {
    int p = blockIdx.x * blockDim.x + threadIdx.x;
    if (p >= NTOT) return;
    int gw = p >> 6;
    int i = p & 63;
    int w = gw & 7;
    int y = (gw >> 3) & (H - 1);
    uint64_t cur = bits[gw];
    uint64_t up  = (y > 0)     ? bits[gw - 8] : 0ull;
    uint64_t dn  = (y < H - 1) ? bits[gw + 8] : 0ull;
    uint64_t prv = (w > 0)     ? bits[gw - 1] : 0ull;
    uint64_t nxt = (w < 7)     ? bits[gw + 1] : 0ull;
    uint64_t d = cur | up | dn | (cur << 1) | (prv >> 63) | (cur >> 1) | (nxt << 63);
    out[p] = ((d >> i) & 1ull) ? 1.0f : 0.0f;
}

// ---------------------------------------------------------------------------
// Host side
// ---------------------------------------------------------------------------
static void run_ccl(const uint64_t* mask, int inv, int* carry, int* labels,
                    int* sizes, int* ncomp, hipStream_t stream) {
    k_init_runs<<<(NROWS + TPB - 1) / TPB, TPB, 0, stream>>>(mask, inv, carry, labels, sizes, ncomp);
    k_merge_runs<<<NBLKW, TPB, 0, stream>>>(mask, inv, carry, labels, 0);
    k_merge_runs<<<NBLKW, TPB, 0, stream>>>(mask, inv, carry, labels, 1);
    k_flatten_count<<<NBLKW, TPB, 0, stream>>>(mask, inv, carry, labels, sizes, ncomp);
}

extern "C" void kernel_launch(void* const* d_in, const int* in_sizes, int n_in,
                              void* d_out, int out_size, void* d_ws, size_t ws_size,
                              hipStream_t stream) {
    const float* in = (const float*)d_in[0];
    float* out = (float*)d_out;

    uint8_t* ws = (uint8_t*)d_ws;
    int* labels = (int*)ws;                                   // 16 MB (sparse use)
    int* sizes  = (int*)(ws + (size_t)NTOT * 4);              // 16 MB (sparse use)
    uint64_t* bitsA = (uint64_t*)(ws + (size_t)NTOT * 8);     // 512 KB
    uint64_t* bitsB = bitsA + NWORDS;                         // 512 KB
    int* carry = (int*)(bitsB + NWORDS);                      // 256 KB
    int* ncomp = carry + NWORDS;                              // 64 B

    // fg = mask > 0, packed
    k_thresh_pack<<<NBLK, TPB, 0, stream>>>(in, bitsA);

    // remove_small_objects(fg, 2000, guard=True): bitsA -> bitsB
    run_ccl(bitsA, 0, carry, labels, sizes, ncomp, stream);
    k_keep_guard<<<NBLKW, TPB, 0, stream>>>(bitsA, carry, labels, sizes, ncomp, 2000, bitsB);

    // remove_small_holes (bg comps < 301 filled): bitsB -> bitsA
    run_ccl(bitsB, 1, carry, labels, sizes, ncomp, stream);
    k_fill_holes<<<NBLKW, TPB, 0, stream>>>(bitsB, carry, labels, sizes, 301, bitsA);

    // erode disk(2): A -> B; opening disk(5): erode B -> A, dilate A -> B
    k_morph_bits<2, true><<<NBLKW, TPB, 0, stream>>>(bitsA, bitsB);
    k_morph_bits<5, true><<<NBLKW, TPB, 0, stream>>>(bitsB, bitsA);
    k_morph_bits<5, false><<<NBLKW, TPB, 0, stream>>>(bitsA, bitsB);

    // remove_small_objects(fg, 2000, guard=True): bitsB -> bitsA
    run_ccl(bitsB, 0, carry, labels, sizes, ncomp, stream);
    k_keep_guard<<<NBLKW, TPB, 0, stream>>>(bitsB, carry, labels, sizes, ncomp, 2000, bitsA);

    // fused dilate disk(1) + cast to float32
    k_to_float_dilate<<<NBLK, TPB, 0, stream>>>(bitsA, out);
}

// Round 7
// 210.709 us; speedup vs baseline: 45.1989x; 1.5351x over previous
//
#include <hip/hip_runtime.h>
#include <stdint.h>

#define BATCH 16
#define H 512
#define W 512
#define HW (H * W)
#define NTOT (BATCH * HW)
#define NWORDS (NTOT / 64)      // 65536 packed words, 8 per row, 4096 per image

#define TPB 256
#define NBLK ((NTOT + TPB - 1) / TPB)
#define NBLKW ((NWORDS + TPB - 1) / TPB)

#define SROWS 16                // strip = 16 rows
#define SWORDS 128              // words per strip
#define SPIX 8192               // pixels per strip
#define NSTRIPS (NWORDS / SWORDS)   // 512 strips (strips never straddle images)

// ---------------------------------------------------------------------------
// Union-find (global): atomicMin keeps parent <= child (monotone), so chains
// are acyclic; stale plain reads only cost retries (any stale parent was once
// a true ancestor -> still same component). find_root_c path-compresses.
// ---------------------------------------------------------------------------
__device__ __forceinline__ int find_root_c(int* L, int x) {
    int r = x, p = L[r];
    while (p != r) { r = p; p = L[r]; }
    if (L[x] != r) atomicMin(&L[x], r);
    return r;
}

__device__ void merge_uf(int* L, int a, int b) {
    while (true) {
        a = find_root_c(L, a);
        b = find_root_c(L, b);
        if (a == b) return;
        int lo = a < b ? a : b;
        int hi = a < b ? b : a;
        int old = atomicMin(&L[hi], lo);
        if (old == hi) return;
        a = lo; b = old;
    }
}

// LDS union-find (same algorithm, ~30cy hops instead of ~400)
__device__ __forceinline__ int find_root_lds(int* P, int x) {
    int r = x, p = P[r];
    while (p != r) { r = p; p = P[r]; }
    return r;
}

__device__ void merge_lds(int* P, int a, int b) {
    while (true) {
        a = find_root_lds(P, a);
        b = find_root_lds(P, b);
        if (a == b) return;
        int lo = a < b ? a : b;
        int hi = a < b ? b : a;
        int old = atomicMin(&P[hi], lo);
        if (old == hi) return;
        a = lo; b = old;
    }
}

// start index of the run containing bit i of word m (base = pixel idx of bit0);
// cv = carry into this word (run start continuing from the left, -1 if none)
__device__ __forceinline__ int start_of(uint64_t m, int i, int cv, int base) {
    uint64_t below = i ? ((~m) & ((1ull << i) - 1)) : 0ull;
    if (below == 0) return (cv >= 0) ? cv : base;  // bits 0..i-1 all ones
    int hz = 63 - __builtin_clzll(below);          // highest zero below i
    return base + hz + 1;
}

// ---------------------------------------------------------------------------
// Kernels — masks bit-packed: bit i of word w = pixel w*64+i.
// ---------------------------------------------------------------------------
__global__ void k_thresh_pack(const float* __restrict__ in, uint64_t* __restrict__ bits) {
    int p = blockIdx.x * blockDim.x + threadIdx.x;
    bool a = (p < NTOT) && (in[p] > 0.0f);
    uint64_t b = __ballot(a);
    if ((threadIdx.x & 63) == 0 && p < NTOT) bits[p >> 6] = b;
}

// Strip-local CCL: one 128-thread block per 16-row strip. Loads words to LDS,
// computes row carries, does ALL intra-strip unions in LDS, then publishes
// L[g_start] = global local-root (depth-1 trees), zeroes root sizes, writes
// carry[] (global pixel index), resets ncomp. Replaces init_runs + merge ph0.
__global__ void k_strip_ccl(const uint64_t* __restrict__ bits, int inv,
                            int* __restrict__ carry, int* __restrict__ L,
                            int* __restrict__ sizes, int* __restrict__ ncomp) {
    __shared__ uint64_t sw[SWORDS];
    __shared__ int scarry[SWORDS];
    __shared__ int par[SPIX];          // sparse: only run-start entries used
    int blk = blockIdx.x;
    int t = threadIdx.x;               // local word index 0..127
    int gw = blk * SWORDS + t;
    uint64_t inv64 = inv ? ~0ull : 0ull;
    uint64_t m = bits[gw] ^ inv64;
    sw[t] = m;
    __syncthreads();

    // per-row carries (threads 0..15, one per row, scan 8 words)
    if (t < SROWS) {
        int cv = -1;
        for (int i = 0; i < 8; ++i) {
            int lw = t * 8 + i;
            scarry[lw] = cv;
            uint64_t w = sw[lw];
            if (w >> 63) {
                uint64_t z = ~w;
                if (z == 0) { if (cv < 0) cv = lw << 6; }
                else { int hz = 63 - __builtin_clzll(z); cv = (lw << 6) + hz + 1; }
            } else cv = -1;
        }
    }
    __syncthreads();

    int cv = scarry[t];
    carry[gw] = (cv >= 0) ? (blk * SPIX + cv) : -1;
    int lbase = t << 6;
    uint64_t starts = m & ~((m << 1) | ((cv >= 0) ? 1ull : 0ull));
    uint64_t ss = starts;
    while (ss) {                       // init parents at run starts
        int s = __builtin_ctzll(ss);
        par[lbase + s] = lbase + s;
        ss &= ss - 1;
    }
    __syncthreads();

    // intra-strip vertical unions (local rows 1..15), one per overlap segment
    if (t >= 8 && m) {
        uint64_t up = sw[t - 8];
        uint64_t cand = m & up;
        if (cand) {
            uint64_t curprev = (t & 7) ? sw[t - 1] : 0ull;
            uint64_t upprev  = (t & 7) ? sw[t - 9] : 0ull;
            uint64_t curl = (m << 1) | (curprev >> 63);
            uint64_t upl  = (up << 1) | (upprev >> 63);
            cand &= ~(curl & upl);
            int cvu = scarry[t - 8];
            while (cand) {
                int i = __builtin_ctzll(cand);
                int sP = start_of(m, i, cv, lbase);
                int sQ = start_of(up, i, cvu, lbase - 512);
                merge_lds(par, sP, sQ);
                cand &= cand - 1;
            }
        }
    }
    __syncthreads();

    // flatten locally + publish depth-1 global trees
    int gpix = blk * SPIX;
    ss = starts;
    while (ss) {
        int s = __builtin_ctzll(ss);
        int ls = lbase + s;
        int r = find_root_lds(par, ls);
        L[gpix + ls] = gpix + r;
        if (r == ls) sizes[gpix + ls] = 0;   // only roots are ever accumulated
        ss &= ss - 1;
    }
    if (t == 0 && (blk & 31) == 0) ncomp[blk >> 5] = 0;  // 32 strips per image
}

// Cross-strip unions: only strip-boundary rows (y%16==0, y!=0). Trees below
// are pre-flattened (depth 1), so chains are short.
__global__ void k_merge_bound(const uint64_t* __restrict__ bits, int inv,
                              const int* __restrict__ carry, int* __restrict__ L) {
    int gw = blockIdx.x * blockDim.x + threadIdx.x;
    if (gw >= NWORDS) return;
    int wrow = gw & 7;
    int y = (gw >> 3) & (H - 1);
    if (y == 0 || (y & (SROWS - 1))) return;
    uint64_t inv64 = inv ? ~0ull : 0ull;
    uint64_t cur = bits[gw] ^ inv64;
    uint64_t up  = bits[gw - 8] ^ inv64;
    uint64_t cand = cur & up;
    if (!cand) return;
    uint64_t curprev = wrow ? (bits[gw - 1] ^ inv64) : 0ull;
    uint64_t upprev  = wrow ? (bits[gw - 9] ^ inv64) : 0ull;
    uint64_t curl = (cur << 1) | (curprev >> 63);
    uint64_t upl  = (up << 1)  | (upprev >> 63);
    cand &= ~(curl & upl);
    if (!cand) return;
    int cvc = carry[gw], cvu = carry[gw - 8];
    int base = gw << 6;
    while (cand) {
        int i = __builtin_ctzll(cand);
        int sP = start_of(cur, i, cvc, base);
        int sQ = start_of(up, i, cvu, base - W);
        merge_uf(L, sP, sQ);
        cand &= cand - 1;
    }
}

// Word-granular flatten + size accumulation. Per-block LDS hash (root->count)
// aggregates the size atomics; flush one global atomicAdd per occupied slot.
__global__ void k_flatten_count(const uint64_t* __restrict__ bits, int inv,
                                const int* __restrict__ carry, int* __restrict__ L,
                                int* __restrict__ sizes, int* __restrict__ ncomp) {
    __shared__ int hk[128];
    __shared__ int hv[128];
    for (int i = threadIdx.x; i < 128; i += TPB) { hk[i] = -1; hv[i] = 0; }
    __syncthreads();

    int gw = blockIdx.x * blockDim.x + threadIdx.x;
    if (gw < NWORDS) {
        uint64_t inv64 = inv ? ~0ull : 0ull;
        uint64_t m = bits[gw] ^ inv64;
        if (m) {
            int cv = carry[gw];
            int base = gw << 6;
            while (m) {
                int s = __builtin_ctzll(m);
                uint64_t rest = m >> s;
                uint64_t nr = ~rest;
                int len = nr ? __builtin_ctzll(nr) : (64 - s);
                uint64_t piece = ((len >= 64) ? ~0ull : ((1ull << len) - 1)) << s;
                bool initial = !(s == 0 && cv >= 0);
                int start = initial ? (base + s) : cv;
                int r = find_root_c(L, start);
                if (initial && r == start) atomicAdd(&ncomp[gw >> 12], 1);
                int cnt = __popcll(piece);
                uint32_t h = ((uint32_t)r * 2654435761u) >> 25;
                bool done = false;
                for (int t = 0; t < 16; ++t) {
                    int slot = (h + t) & 127;
                    int k = hk[slot];
                    if (k == -1) k = atomicCAS(&hk[slot], -1, r);
                    if (k == -1 || k == r) { atomicAdd(&hv[slot], cnt); done = true; break; }
                }
                if (!done) atomicAdd(&sizes[r], cnt);
                m &= ~piece;
            }
        }
    }
    __syncthreads();
    for (int i = threadIdx.x; i < 128; i += TPB)
        if (hk[i] != -1) atomicAdd(&sizes[hk[i]], hv[i]);
}

// remove_small_objects with guard, word-granular (inv=0 CCL data).
__global__ void k_keep_guard(const uint64_t* __restrict__ bits,
                             const int* __restrict__ carry, const int* __restrict__ L,
                             const int* __restrict__ sizes, const int* __restrict__ ncomp,
                             int minsz, uint64_t* __restrict__ out) {
    int gw = blockIdx.x * blockDim.x + threadIdx.x;
    if (gw >= NWORDS) return;
    uint64_t m = bits[gw];
    uint64_t res = m;
    if (m && ncomp[gw >> 12] > 1) {
        int cv = carry[gw];
        int base = gw << 6;
        while (m) {
            int s = __builtin_ctzll(m);
            uint64_t rest = m >> s;
            uint64_t nr = ~rest;
            int len = nr ? __builtin_ctzll(nr) : (64 - s);
            uint64_t piece = ((len >= 64) ? ~0ull : ((1ull << len) - 1)) << s;
            int start = (s == 0 && cv >= 0) ? cv : (base + s);
            int r = L[start];                  // flattened by k_flatten_count
            if (sizes[r] < minsz) res &= ~piece;
            m &= ~piece;
        }
    }
    out[gw] = res;
}

// remove_small_holes: bg components (inv=1 CCL data) smaller than minsz -> fg.
__global__ void k_fill_holes(const uint64_t* __restrict__ bits,
                             const int* __restrict__ carry, const int* __restrict__ L,
                             const int* __restrict__ sizes, int minsz,
                             uint64_t* __restrict__ out) {
    int gw = blockIdx.x * blockDim.x + threadIdx.x;
    if (gw >= NWORDS) return;
    uint64_t fg = bits[gw];
    uint64_t bg = ~fg;
    uint64_t res = fg;
    int cv = carry[gw];
    int base = gw << 6;
    while (bg) {
        int s = __builtin_ctzll(bg);
        uint64_t rest = bg >> s;
        uint64_t nr = ~rest;
        int len = nr ? __builtin_ctzll(nr) : (64 - s);
        uint64_t piece = ((len >= 64) ? ~0ull : ((1ull << len) - 1)) << s;
        int start = (s == 0 && cv >= 0) ? cv : (base + s);
        int r = L[start];
        if (sizes[r] < minsz) res |= piece;
        bg &= ~piece;
    }
    out[gw] = res;
}

// Bit-packed disk morphology. Erode: AND, border = 1s. Dilate: OR, border = 0s.
template <int R, bool ERODE>
__global__ void k_morph_bits(const uint64_t* __restrict__ in, uint64_t* __restrict__ out) {
    int gw = blockIdx.x * blockDim.x + threadIdx.x;
    if (gw >= NWORDS) return;
    int w = gw & 7;
    int y = (gw >> 3) & (H - 1);
    int b = gw >> 12;
    const uint64_t* img = in + (size_t)b * H * 8;
    const uint64_t BORDER = ERODE ? ~0ull : 0ull;
    uint64_t res = ERODE ? ~0ull : 0ull;
#pragma unroll
    for (int dy = -R; dy <= R; ++dy) {
        int yy = y + dy;
        if (yy < 0 || yy >= H) continue;
        int v = R * R - dy * dy;
        int kx = 0;
        while ((kx + 1) * (kx + 1) <= v) ++kx;
        uint64_t cur = img[yy * 8 + w];
        uint64_t prv = (w > 0) ? img[yy * 8 + w - 1] : BORDER;
        uint64_t nxt = (w < 7) ? img[yy * 8 + w + 1] : BORDER;
        uint64_t acc = cur;
#pragma unroll
        for (int dx = 1; dx <= kx; ++dx) {
            uint64_t right = (cur >> dx) | (nxt << (64 - dx));
            uint64_t left  = (cur << dx) | (prv >> (64 - dx));
            if (ERODE) acc &= right & left;
            else       acc |= right | left;
        }
        if (ERODE) res &= acc;
        else       res |= acc;
    }
    out[gw] = res;
}

// Fused dilate(disk1) + float cast: disk(1) is the plus-shaped SE.
__global__ void k_to_float_dilate(const uint64_t* __restrict__ bits,
                                  float* __restrict__ out) {
    int p = blockIdx.x * blockDim.x + threadIdx.x;
    if (p >= NTOT) return;
    int gw = p >> 6;
    int i = p & 63;
    int w = gw & 7;
    int y = (gw >> 3) & (H - 1);
    uint64_t cur = bits[gw];
    uint64_t up  = (y > 0)     ? bits[gw - 8] : 0ull;
    uint64_t dn  = (y < H - 1) ? bits[gw + 8] : 0ull;
    uint64_t prv = (w > 0)     ? bits[gw - 1] : 0ull;
    uint64_t nxt = (w < 7)     ? bits[gw + 1] : 0ull;
    uint64_t d = cur | up | dn | (cur << 1) | (prv >> 63) | (cur >> 1) | (nxt << 63);
    out[p] = ((d >> i) & 1ull) ? 1.0f : 0.0f;
}

// ---------------------------------------------------------------------------
// Host side
// ---------------------------------------------------------------------------
static void run_ccl(const uint64_t* mask, int inv, int* carry, int* labels,
                    int* sizes, int* ncomp, hipStream_t stream) {
    k_strip_ccl<<<NSTRIPS, SWORDS, 0, stream>>>(mask, inv, carry, labels, sizes, ncomp);
    k_merge_bound<<<NBLKW, TPB, 0, stream>>>(mask, inv, carry, labels);
    k_flatten_count<<<NBLKW, TPB, 0, stream>>>(mask, inv, carry, labels, sizes, ncomp);
}

extern "C" void kernel_launch(void* const* d_in, const int* in_sizes, int n_in,
                              void* d_out, int out_size, void* d_ws, size_t ws_size,
                              hipStream_t stream) {
    const float* in = (const float*)d_in[0];
    float* out = (float*)d_out;

    uint8_t* ws = (uint8_t*)d_ws;
    int* labels = (int*)ws;                                   // 16 MB (sparse use)
    int* sizes  = (int*)(ws + (size_t)NTOT * 4);              // 16 MB (sparse use)
    uint64_t* bitsA = (uint64_t*)(ws + (size_t)NTOT * 8);     // 512 KB
    uint64_t* bitsB = bitsA + NWORDS;                         // 512 KB
    int* carry = (int*)(bitsB + NWORDS);                      // 256 KB
    int* ncomp = carry + NWORDS;                              // 64 B

    // fg = mask > 0, packed
    k_thresh_pack<<<NBLK, TPB, 0, stream>>>(in, bitsA);

    // remove_small_objects(fg, 2000, guard=True): bitsA -> bitsB
    run_ccl(bitsA, 0, carry, labels, sizes, ncomp, stream);
    k_keep_guard<<<NBLKW, TPB, 0, stream>>>(bitsA, carry, labels, sizes, ncomp, 2000, bitsB);

    // remove_small_holes (bg comps < 301 filled): bitsB -> bitsA
    run_ccl(bitsB, 1, carry, labels, sizes, ncomp, stream);
    k_fill_holes<<<NBLKW, TPB, 0, stream>>>(bitsB, carry, labels, sizes, 301, bitsA);

    // erode disk(2): A -> B; opening disk(5): erode B -> A, dilate A -> B
    k_morph_bits<2, true><<<NBLKW, TPB, 0, stream>>>(bitsA, bitsB);
    k_morph_bits<5, true><<<NBLKW, TPB, 0, stream>>>(bitsB, bitsA);
    k_morph_bits<5, false><<<NBLKW, TPB, 0, stream>>>(bitsA, bitsB);

    // remove_small_objects(fg, 2000, guard=True): bitsB -> bitsA
    run_ccl(bitsB, 0, carry, labels, sizes, ncomp, stream);
    k_keep_guard<<<NBLKW, TPB, 0, stream>>>(bitsB, carry, labels, sizes, ncomp, 2000, bitsA);

    // fused dilate disk(1) + cast to float32
    k_to_float_dilate<<<NBLK, TPB, 0, stream>>>(bitsA, out);
}